// Round 6
// baseline (437.616 us; speedup 1.0000x reference)
//
#include <hip/hip_runtime.h>
#include <math.h>

#define Bn 32
#define Pn 32768
#define On 32
#define NBLK 1024          // 32 chunks x 32 batches = 4 blocks/CU on 256 CUs
#define NBINS 2048         // histogram bins: key = float_bits >> 20
#define CANDCAP 4096

// d_ws layout:
// [0,     8192)    u64   bpm[Bn*On]     packed (iou_bits<<32 | (Pn-1-p))
// [8192,  8320)    int   num_pos[Bn]
// [8320,  8332)    float loss_l, float ce_t, int np_tot
// [8336,  8348)    int   bar[3]         grid-barrier counters
// [16384, 278528)  int   hist[Bn][NBINS]
// [278528, +4MB)   float ce_mine[Bn*Pn]
// memsetAsync zeroes [0, 278528) each launch.

__device__ __forceinline__ void gbar(int* ctr, int tid) {
    __syncthreads();
    if (tid == 0) {
        __threadfence();   // release: flush this block's stores device-wide
        __hip_atomic_fetch_add(ctr, 1, __ATOMIC_RELEASE, __HIP_MEMORY_SCOPE_AGENT);
        while (__hip_atomic_load(ctr, __ATOMIC_ACQUIRE, __HIP_MEMORY_SCOPE_AGENT) < NBLK)
            __builtin_amdgcn_s_sleep(1);
        __threadfence();   // acquire: invalidate stale cache lines
    }
    __syncthreads();
}

__global__ __launch_bounds__(256, 4) void fused(
    const float* __restrict__ loc, const float4* __restrict__ conf4,
    const float4* __restrict__ priors, const float* __restrict__ targets,
    unsigned long long* __restrict__ bpm, int* __restrict__ num_pos,
    float* __restrict__ loss_l_t, float* __restrict__ ce_t,
    int* __restrict__ np_tot, int* __restrict__ bar, int* __restrict__ hist,
    float* __restrict__ ce_mine, float* __restrict__ out)
{
    const int bid = blockIdx.x;
    const int c = bid & 31, b = bid >> 5;
    const int tid = threadIdx.x;
    const int lane = tid & 63, wv = tid >> 6;

    __shared__ float4 tb[On];
    __shared__ float  ta_lb[On];            // area (stage1) -> label (stage2)
    __shared__ unsigned long long wred[On][4];
    __shared__ int    forced[1024];         // stage2 forced; stage3 scan scratch
    __shared__ float  sred[12];
    __shared__ int    shist[NBINS];         // stage3 only
    __shared__ float  cand[CANDCAP];        // stage3 candidates; stage2 lhist alias
    __shared__ int    s3i[4];
    __shared__ float  s3f[2];
    __shared__ int    ired[4];
    __shared__ float  fred[4];

    if (tid < On) {
        const float* t = targets + ((size_t)b * On + tid) * 5;
        float x1 = t[0], y1 = t[1], x2 = t[2], y2 = t[3];
        tb[tid] = make_float4(x1, y1, x2, y2);
        ta_lb[tid] = (x2 - x1) * (y2 - y1);
    }
    __syncthreads();

    // ---------- stage 1: IoU pass; per-p argmax (regs) + per-o argmax (bpm) ----------
    const int base = c * 1024;
    const int p0 = base + tid * 4;
    float px1[4], py1[4], px2[4], py2[4], ab[4];
#pragma unroll
    for (int j = 0; j < 4; j++) {
        float4 pr = priors[p0 + j];
        px1[j] = pr.x - pr.z * 0.5f; py1[j] = pr.y - pr.w * 0.5f;
        px2[j] = pr.x + pr.z * 0.5f; py2[j] = pr.y + pr.w * 0.5f;
        ab[j]  = (px2[j] - px1[j]) * (py2[j] - py1[j]);
    }
    float bI[4] = {0.f, 0.f, 0.f, 0.f};
    float bU[4] = {1.f, 1.f, 1.f, 1.f};
    int   bx[4] = {0, 0, 0, 0};

    for (int o = 0; o < On; o++) {
        float4 tt = tb[o];
        float  a  = ta_lb[o];
        float I[4], U[4];
#pragma unroll
        for (int j = 0; j < 4; j++) {
            float ix1 = fmaxf(tt.x, px1[j]), iy1 = fmaxf(tt.y, py1[j]);
            float ix2 = fminf(tt.z, px2[j]), iy2 = fminf(tt.w, py2[j]);
            float iw = fmaxf(ix2 - ix1, 0.f), ih = fmaxf(iy2 - iy1, 0.f);
            I[j] = iw * ih;
            U[j] = a + ab[j] - I[j];
            if (I[j] * bU[j] > bI[j] * U[j]) { bI[j] = I[j]; bU[j] = U[j]; bx[j] = o; }
        }
        float cI = I[0], cU = U[0]; int cp = p0;    // first-wins over ascending p
#pragma unroll
        for (int j = 1; j < 4; j++)
            if (I[j] * cU > cI * U[j]) { cI = I[j]; cU = U[j]; cp = p0 + j; }
        float iou = cI / cU;                        // f32 quotient for ref tie semantics
        unsigned long long key = ((unsigned long long)__float_as_uint(iou) << 32)
                               | (unsigned)(Pn - 1 - cp);
#pragma unroll
        for (int off = 32; off > 0; off >>= 1) {
            unsigned long long ok = __shfl_down(key, off, 64);
            if (ok > key) key = ok;
        }
        if (lane == 0) wred[o][wv] = key;
    }
    __syncthreads();
    if (tid < On) {
        unsigned long long kk = wred[tid][0];
#pragma unroll
        for (int w = 1; w < 4; w++) if (wred[tid][w] > kk) kk = wred[tid][w];
        atomicMax(&bpm[b * On + tid], kk);
    }
    int flags = 0;
#pragma unroll
    for (int j = 0; j < 4; j++) if (bI[j] >= 0.5f * bU[j]) flags |= 1 << j;

    gbar(&bar[0], tid);

    // ---------- stage 2: forced override, losses, ce_mine, histogram ----------
    forced[tid] = -1; forced[tid + 256] = -1; forced[tid + 512] = -1; forced[tid + 768] = -1;
    int* lhist = (int*)cand;
    for (int i = tid; i < NBINS; i += 256) lhist[i] = 0;
    int sp = -1;
    if (tid < On) {
        ta_lb[tid] = targets[((size_t)b * On + tid) * 5 + 4];   // labels
        sp = Pn - 1 - (int)(bpm[b * On + tid] & 0xFFFFFFFFull);
    }
    __syncthreads();
    if (tid < On && sp >= base && sp < base + 1024)
        atomicMax(&forced[sp - base], tid);          // max o == numpy last write
    __syncthreads();

    size_t cb = ((size_t)b * Pn + p0) >> 1;
    float4 cA = conf4[cb], cB = conf4[cb + 1];
    float c0a[4] = {cA.x, cA.z, cB.x, cB.z};
    float c1a[4] = {cA.y, cA.w, cB.y, cB.w};
    float cem[4];
    float ll_s = 0.f, pce_s = 0.f, cnt_s = 0.f;

#pragma unroll
    for (int j = 0; j < 4; j++) {
        int fo = forced[tid * 4 + j];
        int bidx = (fo >= 0) ? fo : bx[j];
        int cf = ((fo >= 0) || ((flags >> j) & 1)) ? (int)ta_lb[bidx] : 0;
        bool pos = cf > 0;
        if (pos) {
            float4 tt = tb[bidx];
            float4 pr = priors[p0 + j];
            float g0 = ((tt.x + tt.z) * 0.5f - pr.x) / (0.1f * pr.z);
            float g1 = ((tt.y + tt.w) * 0.5f - pr.y) / (0.1f * pr.w);
            float g2 = __logf((tt.z - tt.x) / pr.z) * 5.0f;
            float g3 = __logf((tt.w - tt.y) / pr.w) * 5.0f;
            const float* lp = loc + ((size_t)b * Pn + p0 + j) * 3;
            float q0 = lp[0], q1 = lp[1], q2 = lp[2];
            float dd[4] = { q0 - g0, q1 - g1, q2 - g2, q2 - g3 };
#pragma unroll
            for (int i = 0; i < 4; i++) {
                float ad = fabsf(dd[i]);
                ll_s += (ad < 1.f) ? 0.5f * dd[i] * dd[i] : (ad - 0.5f);
            }
            cnt_s += 1.f;
        }
        float m = fmaxf(c0a[j], c1a[j]);
        float lse = m + __logf(__expf(c0a[j] - m) + __expf(c1a[j] - m));
        float ce = lse - (cf ? c1a[j] : c0a[j]);
        if (pos) { pce_s += ce; ce = 0.f; }
        cem[j] = fmaxf(ce, 0.f);
        atomicAdd(&lhist[__float_as_uint(cem[j]) >> 20], 1);
    }
    ((float4*)ce_mine)[((size_t)b * Pn + p0) >> 2] = make_float4(cem[0], cem[1], cem[2], cem[3]);

#pragma unroll
    for (int off = 32; off > 0; off >>= 1) {
        ll_s  += __shfl_down(ll_s,  off, 64);
        pce_s += __shfl_down(pce_s, off, 64);
        cnt_s += __shfl_down(cnt_s, off, 64);
    }
    if (lane == 0) { sred[wv*3] = ll_s; sred[wv*3+1] = pce_s; sred[wv*3+2] = cnt_s; }
    __syncthreads();
    if (tid == 0) {
        float llr = 0, pcer = 0, cntr = 0;
        for (int w = 0; w < 4; w++) { llr += sred[w*3]; pcer += sred[w*3+1]; cntr += sred[w*3+2]; }
        if (llr != 0.f)  atomicAdd(loss_l_t, llr);
        if (pcer != 0.f) atomicAdd(ce_t, pcer);
        int cc = (int)cntr;
        if (cc) { atomicAdd(&num_pos[b], cc); atomicAdd(np_tot, cc); }
    }
    for (int i = tid; i < NBINS; i += 256) {
        int v = lhist[i];
        if (v) atomicAdd(&hist[b * NBINS + i], v);
    }

    gbar(&bar[1], tid);

    // ---------- stage 3: per-batch exact top-k sum (32 blocks active) ----------
    if (bid < Bn) {
        int b3 = bid;
        int k = 3 * num_pos[b3];
        if (k > Pn - 1) k = Pn - 1;
        if (k > 0) {
            const int* gh = hist + b3 * NBINS;
            for (int i = tid; i < NBINS; i += 256) shist[i] = gh[i];
            __syncthreads();
            int ps = 0;
#pragma unroll
            for (int i = 0; i < 8; i++) ps += shist[tid * 8 + i];
            forced[tid] = ps;
            __syncthreads();
            if (tid == 0) {
                int cacc = 0, m = 0, cab = 0;
                for (int t = 255; t >= 0; t--) {
                    if (cacc + forced[t] >= k) {
                        for (int i = t * 8 + 7; i >= t * 8; i--) {
                            if (cacc + shist[i] >= k) { m = i; cab = cacc; break; }
                            cacc += shist[i];
                        }
                        break;
                    }
                    cacc += forced[t];
                }
                s3i[0] = m; s3i[1] = cab; s3i[2] = 0;
            }
            __syncthreads();
            const int m = s3i[0], cab = s3i[1], kk = k - cab;
            const int cntm = shist[m];
            const float4* v4 = (const float4*)(ce_mine + (size_t)b3 * Pn);

            if (cntm <= CANDCAP) {
                float shi = 0.f;
                for (int i = 0; i < 32; i++) {
                    float4 r = v4[i * 256 + tid];
                    float vv[4] = {r.x, r.y, r.z, r.w};
#pragma unroll
                    for (int q = 0; q < 4; q++) {
                        int kb = (int)(__float_as_uint(vv[q]) >> 20);
                        if (kb > m) shi += vv[q];
                        else if (kb == m) cand[atomicAdd(&s3i[2], 1)] = vv[q];
                    }
                }
#pragma unroll
                for (int off = 32; off > 0; off >>= 1) shi += __shfl_down(shi, off, 64);
                if (lane == 0) fred[wv] = shi;
                __syncthreads();
                if (tid == 0) s3f[0] = fred[0] + fred[1] + fred[2] + fred[3];
                int n = s3i[2];
                unsigned lo = (unsigned)m << 20, hi = ((unsigned)m + 1u) << 20;
                __syncthreads();
                while (hi - lo > 1u) {
                    unsigned mid = lo + ((hi - lo) >> 1);
                    float mf = __uint_as_float(mid);
                    int ccc = 0;
                    for (int i = tid; i < n; i += 256) ccc += (cand[i] > mf);
#pragma unroll
                    for (int off = 32; off > 0; off >>= 1) ccc += __shfl_down(ccc, off, 64);
                    if (lane == 0) ired[wv] = ccc;
                    __syncthreads();
                    int tot = ired[0] + ired[1] + ired[2] + ired[3];
                    __syncthreads();
                    if (tot == kk) { hi = mid; break; }
                    if (tot >= kk) lo = mid; else hi = mid;
                }
                float tv = __uint_as_float(hi);
                float s = 0.f; int ct = 0;
                for (int i = tid; i < n; i += 256) {
                    float v = cand[i];
                    if (v > tv) { s += v; ct++; }
                }
#pragma unroll
                for (int off = 32; off > 0; off >>= 1) {
                    s += __shfl_down(s, off, 64); ct += __shfl_down(ct, off, 64);
                }
                if (lane == 0) { fred[wv] = s; ired[wv] = ct; }
                __syncthreads();
                if (tid == 0) {
                    float st = fred[0] + fred[1] + fred[2] + fred[3];
                    int ctt = ired[0] + ired[1] + ired[2] + ired[3];
                    atomicAdd(ce_t, s3f[0] + st + (float)(kk - ctt) * tv);
                }
            } else {
                // fallback: bisection within the cut bin over global data (pathological)
                unsigned lo = (unsigned)m << 20, hi = ((unsigned)m + 1u) << 20;
                while (hi - lo > 1u) {
                    unsigned mid = lo + ((hi - lo) >> 1);
                    float mf = __uint_as_float(mid);
                    int ccc = 0;
                    for (int i = 0; i < 32; i++) {
                        float4 r = v4[i * 256 + tid];
                        ccc += (r.x > mf) + (r.y > mf) + (r.z > mf) + (r.w > mf);
                    }
#pragma unroll
                    for (int off = 32; off > 0; off >>= 1) ccc += __shfl_down(ccc, off, 64);
                    if (lane == 0) ired[wv] = ccc;
                    __syncthreads();
                    int tot = ired[0] + ired[1] + ired[2] + ired[3];
                    __syncthreads();
                    if (tot == k) { hi = mid; break; }
                    if (tot >= k) lo = mid; else hi = mid;
                }
                float tv = __uint_as_float(hi);
                float s = 0.f; int ct = 0;
                for (int i = 0; i < 32; i++) {
                    float4 r = v4[i * 256 + tid];
                    if (r.x > tv) { s += r.x; ct++; }
                    if (r.y > tv) { s += r.y; ct++; }
                    if (r.z > tv) { s += r.z; ct++; }
                    if (r.w > tv) { s += r.w; ct++; }
                }
#pragma unroll
                for (int off = 32; off > 0; off >>= 1) {
                    s += __shfl_down(s, off, 64); ct += __shfl_down(ct, off, 64);
                }
                if (lane == 0) { fred[wv] = s; ired[wv] = ct; }
                __syncthreads();
                if (tid == 0) {
                    float st = fred[0] + fred[1] + fred[2] + fred[3];
                    int ctt = ired[0] + ired[1] + ired[2] + ired[3];
                    atomicAdd(ce_t, st + (float)(k - ctt) * tv);
                }
            }
        }
    }

    // ---------- final: arrive; block 0 waits and finalizes ----------
    __syncthreads();
    if (tid == 0) {
        __threadfence();
        __hip_atomic_fetch_add(&bar[2], 1, __ATOMIC_RELEASE, __HIP_MEMORY_SCOPE_AGENT);
        if (bid == 0) {
            while (__hip_atomic_load(&bar[2], __ATOMIC_ACQUIRE, __HIP_MEMORY_SCOPE_AGENT) < NBLK)
                __builtin_amdgcn_s_sleep(1);
            __threadfence();
            float N = (float)(*np_tot);
            out[0] = *loss_l_t / N;
            out[1] = *ce_t / N;
        }
    }
}

extern "C" void kernel_launch(void* const* d_in, const int* in_sizes, int n_in,
                              void* d_out, int out_size, void* d_ws, size_t ws_size,
                              hipStream_t stream) {
    const float*  loc     = (const float*)d_in[0];   // (B,P,3)
    const float4* conf4   = (const float4*)d_in[1];  // (B,P,2)
    const float4* priors  = (const float4*)d_in[2];  // (P,4)
    const float*  targets = (const float*)d_in[3];   // (B,O,5)
    float* out = (float*)d_out;

    char* ws = (char*)d_ws;
    unsigned long long* bpm = (unsigned long long*)ws;
    int*   num_pos  = (int*)(ws + 8192);
    float* loss_l_t = (float*)(ws + 8320);
    float* ce_t     = (float*)(ws + 8324);
    int*   np_tot   = (int*)(ws + 8328);
    int*   bar      = (int*)(ws + 8336);
    int*   hist     = (int*)(ws + 16384);
    float* ce_mine  = (float*)(ws + 16384 + (size_t)Bn * NBINS * 4);

    // zero bpm/accumulators/barrier counters/histogram (ws is poisoned 0xAA)
    hipMemsetAsync(ws, 0, 16384 + (size_t)Bn * NBINS * 4, stream);

    hipLaunchKernelGGL(fused, dim3(NBLK), dim3(256), 0, stream,
                       loc, conf4, priors, targets, bpm, num_pos,
                       loss_l_t, ce_t, np_tot, bar, hist, ce_mine, out);
}

// Round 7
// 255.318 us; speedup vs baseline: 1.7140x; 1.7140x over previous
//
#include <hip/hip_runtime.h>
#include <math.h>

#define Bn 32
#define Pn 32768
#define On 32
#define NBLK 1024          // 32 chunks x 32 batches = 4 blocks/CU on 256 CUs
#define NBINS 2048         // histogram bins: key = float_bits >> 20
#define CANDCAP 4096

// d_ws layout:
// [0,     8192)    u64   bpm[Bn*On]     packed (iou_bits<<32 | (Pn-1-p))
// [8192,  8320)    int   num_pos[Bn]
// [8320,  8336)    float loss_l, ce_t; int np_tot, done
// [8448,  12544)   int   barc[Bn] strided 32 ints (128 B apart)
// [16384, 278528)  int   hist[Bn][NBINS]
// [278528, +4MB)   float ce_mine[Bn*Pn]
// memsetAsync zeroes [0, 278528) each launch.

__global__ __launch_bounds__(256, 4) void fused(
    const float* __restrict__ loc, const float4* __restrict__ conf4,
    const float4* __restrict__ priors, const float* __restrict__ targets,
    unsigned long long* __restrict__ bpm, int* __restrict__ num_pos,
    float* __restrict__ loss_l_t, float* __restrict__ ce_t,
    int* __restrict__ np_tot, int* __restrict__ done, int* __restrict__ barc,
    int* __restrict__ hist, float* __restrict__ ce_mine, float* __restrict__ out)
{
    const int bid = blockIdx.x;
    const int c = bid & 31, b = bid >> 5;
    const int tid = threadIdx.x;
    const int lane = tid & 63, wv = tid >> 6;
    int* bctr = barc + b * 32;              // this batch's padded counter

    __shared__ float4 tb[On];
    __shared__ float  ta_lb[On];            // area (stage1) -> label (stage2)
    __shared__ unsigned long long wred[On][4];
    __shared__ int    forced[1024];         // stage2 forced; stage3 scan scratch
    __shared__ float  sred[12];
    __shared__ int    shist[NBINS];         // stage3 only
    __shared__ float  cand[CANDCAP];        // stage3 candidates; stage2 lhist alias
    __shared__ int    s3i[4];
    __shared__ float  s3f[2];
    __shared__ int    ired[4];
    __shared__ float  fred[4];
    __shared__ int    s_last;

    if (tid < On) {
        const float* t = targets + ((size_t)b * On + tid) * 5;
        float x1 = t[0], y1 = t[1], x2 = t[2], y2 = t[3];
        tb[tid] = make_float4(x1, y1, x2, y2);
        ta_lb[tid] = (x2 - x1) * (y2 - y1);
    }
    __syncthreads();

    // ---------- stage 1: IoU pass; per-p argmax (regs) + per-o argmax (bpm) ----------
    const int base = c * 1024;
    const int p0 = base + tid * 4;
    float px1[4], py1[4], px2[4], py2[4], ab[4];
#pragma unroll
    for (int j = 0; j < 4; j++) {
        float4 pr = priors[p0 + j];
        px1[j] = pr.x - pr.z * 0.5f; py1[j] = pr.y - pr.w * 0.5f;
        px2[j] = pr.x + pr.z * 0.5f; py2[j] = pr.y + pr.w * 0.5f;
        ab[j]  = (px2[j] - px1[j]) * (py2[j] - py1[j]);
    }
    float bI[4] = {0.f, 0.f, 0.f, 0.f};
    float bU[4] = {1.f, 1.f, 1.f, 1.f};
    int   bx[4] = {0, 0, 0, 0};

    for (int o = 0; o < On; o++) {
        float4 tt = tb[o];
        float  a  = ta_lb[o];
        float I[4], U[4];
#pragma unroll
        for (int j = 0; j < 4; j++) {
            float ix1 = fmaxf(tt.x, px1[j]), iy1 = fmaxf(tt.y, py1[j]);
            float ix2 = fminf(tt.z, px2[j]), iy2 = fminf(tt.w, py2[j]);
            float iw = fmaxf(ix2 - ix1, 0.f), ih = fmaxf(iy2 - iy1, 0.f);
            I[j] = iw * ih;
            U[j] = a + ab[j] - I[j];
            if (I[j] * bU[j] > bI[j] * U[j]) { bI[j] = I[j]; bU[j] = U[j]; bx[j] = o; }
        }
        float cI = I[0], cU = U[0]; int cp = p0;    // first-wins over ascending p
#pragma unroll
        for (int j = 1; j < 4; j++)
            if (I[j] * cU > cI * U[j]) { cI = I[j]; cU = U[j]; cp = p0 + j; }
        float iou = cI / cU;                        // f32 quotient for ref tie semantics
        // f32 butterfly max + ballot: lanes ordered by p, lowest set bit = lowest p
        float wmax = iou;
#pragma unroll
        for (int off = 1; off < 64; off <<= 1)
            wmax = fmaxf(wmax, __shfl_xor(wmax, off, 64));
        unsigned long long ball = __ballot(iou == wmax);
        int src = __ffsll((unsigned long long)ball) - 1;
        if (lane == src)
            wred[o][wv] = ((unsigned long long)__float_as_uint(iou) << 32)
                        | (unsigned)(Pn - 1 - cp);
    }
    __syncthreads();
    if (tid < On) {
        unsigned long long kk = wred[tid][0];
#pragma unroll
        for (int w = 1; w < 4; w++) if (wred[tid][w] > kk) kk = wred[tid][w];
        atomicMax(&bpm[b * On + tid], kk);
    }
    int flags = 0;
#pragma unroll
    for (int j = 0; j < 4; j++) if (bI[j] >= 0.5f * bU[j]) flags |= 1 << j;

    // ---------- barrier 1: per-batch (32 pollers on a padded counter) ----------
    __syncthreads();          // drains all vmem (incl. atomicMax) before arrival
    if (tid == 0) {
        __threadfence();
        __hip_atomic_fetch_add(bctr, 1, __ATOMIC_RELEASE, __HIP_MEMORY_SCOPE_AGENT);
        while (__hip_atomic_load(bctr, __ATOMIC_ACQUIRE, __HIP_MEMORY_SCOPE_AGENT) < 32)
            __builtin_amdgcn_s_sleep(2);
        __threadfence();
    }
    __syncthreads();

    // ---------- stage 2: forced override, losses, ce_mine, histogram ----------
    size_t cb = ((size_t)b * Pn + p0) >> 1;
    float4 cA = conf4[cb], cB = conf4[cb + 1];      // issue early

    forced[tid] = -1; forced[tid + 256] = -1; forced[tid + 512] = -1; forced[tid + 768] = -1;
    int* lhist = (int*)cand;
    for (int i = tid; i < NBINS; i += 256) lhist[i] = 0;
    int sp = -1;
    if (tid < On) {
        ta_lb[tid] = targets[((size_t)b * On + tid) * 5 + 4];   // labels
        sp = Pn - 1 - (int)(bpm[b * On + tid] & 0xFFFFFFFFull);
    }
    __syncthreads();
    if (tid < On && sp >= base && sp < base + 1024)
        atomicMax(&forced[sp - base], tid);          // max o == numpy last write
    __syncthreads();

    float c0a[4] = {cA.x, cA.z, cB.x, cB.z};
    float c1a[4] = {cA.y, cA.w, cB.y, cB.w};
    float cem[4];
    float ll_s = 0.f, pce_s = 0.f, cnt_s = 0.f;

#pragma unroll
    for (int j = 0; j < 4; j++) {
        int fo = forced[tid * 4 + j];
        int bidx = (fo >= 0) ? fo : bx[j];
        int cf = ((fo >= 0) || ((flags >> j) & 1)) ? (int)ta_lb[bidx] : 0;
        bool pos = cf > 0;
        if (pos) {
            float4 tt = tb[bidx];
            float4 pr = priors[p0 + j];
            float g0 = ((tt.x + tt.z) * 0.5f - pr.x) / (0.1f * pr.z);
            float g1 = ((tt.y + tt.w) * 0.5f - pr.y) / (0.1f * pr.w);
            float g2 = __logf((tt.z - tt.x) / pr.z) * 5.0f;
            float g3 = __logf((tt.w - tt.y) / pr.w) * 5.0f;
            const float* lp = loc + ((size_t)b * Pn + p0 + j) * 3;
            float q0 = lp[0], q1 = lp[1], q2 = lp[2];
            float dd[4] = { q0 - g0, q1 - g1, q2 - g2, q2 - g3 };
#pragma unroll
            for (int i = 0; i < 4; i++) {
                float ad = fabsf(dd[i]);
                ll_s += (ad < 1.f) ? 0.5f * dd[i] * dd[i] : (ad - 0.5f);
            }
            cnt_s += 1.f;
        }
        float m = fmaxf(c0a[j], c1a[j]);
        float lse = m + __logf(__expf(c0a[j] - m) + __expf(c1a[j] - m));
        float ce = lse - (cf ? c1a[j] : c0a[j]);
        if (pos) { pce_s += ce; ce = 0.f; }
        cem[j] = fmaxf(ce, 0.f);
        atomicAdd(&lhist[__float_as_uint(cem[j]) >> 20], 1);
    }
    ((float4*)ce_mine)[((size_t)b * Pn + p0) >> 2] = make_float4(cem[0], cem[1], cem[2], cem[3]);

#pragma unroll
    for (int off = 32; off > 0; off >>= 1) {
        ll_s  += __shfl_down(ll_s,  off, 64);
        pce_s += __shfl_down(pce_s, off, 64);
        cnt_s += __shfl_down(cnt_s, off, 64);
    }
    if (lane == 0) { sred[wv*3] = ll_s; sred[wv*3+1] = pce_s; sred[wv*3+2] = cnt_s; }
    __syncthreads();
    if (tid == 0) {
        float llr = 0, pcer = 0, cntr = 0;
        for (int w = 0; w < 4; w++) { llr += sred[w*3]; pcer += sred[w*3+1]; cntr += sred[w*3+2]; }
        if (llr != 0.f)  atomicAdd(loss_l_t, llr);
        if (pcer != 0.f) atomicAdd(ce_t, pcer);
        int cc = (int)cntr;
        if (cc) { atomicAdd(&num_pos[b], cc); atomicAdd(np_tot, cc); }
    }
    for (int i = tid; i < NBINS; i += 256) {
        int v = lhist[i];
        if (v) atomicAdd(&hist[b * NBINS + i], v);
    }

    // ---------- barrier 2: last-arrival, no polling ----------
    __syncthreads();          // all stage2 stores/atomics drained
    if (tid == 0) {
        __threadfence();
        int old = __hip_atomic_fetch_add(bctr, 1, __ATOMIC_ACQ_REL, __HIP_MEMORY_SCOPE_AGENT);
        s_last = (old == 63);                 // counter reused: 32..63 in phase 2
        __threadfence();
    }
    __syncthreads();

    // ---------- stage 3: per-batch exact top-k (last-arriving block only) ----------
    if (s_last) {
        int k = 3 * num_pos[b];
        if (k > Pn - 1) k = Pn - 1;
        if (k > 0) {
            const int* gh = hist + b * NBINS;
            for (int i = tid; i < NBINS; i += 256) shist[i] = gh[i];
            __syncthreads();
            int ps = 0;
#pragma unroll
            for (int i = 0; i < 8; i++) ps += shist[tid * 8 + i];
            forced[tid] = ps;
            __syncthreads();
            if (tid == 0) {
                int cacc = 0, m = 0, cab = 0;
                for (int t = 255; t >= 0; t--) {
                    if (cacc + forced[t] >= k) {
                        for (int i = t * 8 + 7; i >= t * 8; i--) {
                            if (cacc + shist[i] >= k) { m = i; cab = cacc; break; }
                            cacc += shist[i];
                        }
                        break;
                    }
                    cacc += forced[t];
                }
                s3i[0] = m; s3i[1] = cab; s3i[2] = 0;
            }
            __syncthreads();
            const int m = s3i[0], cab = s3i[1], kk = k - cab;
            const int cntm = shist[m];
            const float4* v4 = (const float4*)(ce_mine + (size_t)b * Pn);

            if (cntm <= CANDCAP) {
                float shi = 0.f;
                for (int i = 0; i < 32; i++) {
                    float4 r = v4[i * 256 + tid];
                    float vv[4] = {r.x, r.y, r.z, r.w};
#pragma unroll
                    for (int q = 0; q < 4; q++) {
                        int kb = (int)(__float_as_uint(vv[q]) >> 20);
                        if (kb > m) shi += vv[q];
                        else if (kb == m) cand[atomicAdd(&s3i[2], 1)] = vv[q];
                    }
                }
#pragma unroll
                for (int off = 32; off > 0; off >>= 1) shi += __shfl_down(shi, off, 64);
                if (lane == 0) fred[wv] = shi;
                __syncthreads();
                if (tid == 0) s3f[0] = fred[0] + fred[1] + fred[2] + fred[3];
                int n = s3i[2];
                unsigned lo = (unsigned)m << 20, hi = ((unsigned)m + 1u) << 20;
                __syncthreads();
                while (hi - lo > 1u) {
                    unsigned mid = lo + ((hi - lo) >> 1);
                    float mf = __uint_as_float(mid);
                    int ccc = 0;
                    for (int i = tid; i < n; i += 256) ccc += (cand[i] > mf);
#pragma unroll
                    for (int off = 32; off > 0; off >>= 1) ccc += __shfl_down(ccc, off, 64);
                    if (lane == 0) ired[wv] = ccc;
                    __syncthreads();
                    int tot = ired[0] + ired[1] + ired[2] + ired[3];
                    __syncthreads();
                    if (tot == kk) { hi = mid; break; }
                    if (tot >= kk) lo = mid; else hi = mid;
                }
                float tv = __uint_as_float(hi);
                float s = 0.f; int ct = 0;
                for (int i = tid; i < n; i += 256) {
                    float v = cand[i];
                    if (v > tv) { s += v; ct++; }
                }
#pragma unroll
                for (int off = 32; off > 0; off >>= 1) {
                    s += __shfl_down(s, off, 64); ct += __shfl_down(ct, off, 64);
                }
                if (lane == 0) { fred[wv] = s; ired[wv] = ct; }
                __syncthreads();
                if (tid == 0) {
                    float st = fred[0] + fred[1] + fred[2] + fred[3];
                    int ctt = ired[0] + ired[1] + ired[2] + ired[3];
                    atomicAdd(ce_t, s3f[0] + st + (float)(kk - ctt) * tv);
                }
            } else {
                // fallback: bisection within the cut bin over global data (pathological)
                unsigned lo = (unsigned)m << 20, hi = ((unsigned)m + 1u) << 20;
                while (hi - lo > 1u) {
                    unsigned mid = lo + ((hi - lo) >> 1);
                    float mf = __uint_as_float(mid);
                    int ccc = 0;
                    for (int i = 0; i < 32; i++) {
                        float4 r = v4[i * 256 + tid];
                        ccc += (r.x > mf) + (r.y > mf) + (r.z > mf) + (r.w > mf);
                    }
#pragma unroll
                    for (int off = 32; off > 0; off >>= 1) ccc += __shfl_down(ccc, off, 64);
                    if (lane == 0) ired[wv] = ccc;
                    __syncthreads();
                    int tot = ired[0] + ired[1] + ired[2] + ired[3];
                    __syncthreads();
                    if (tot == k) { hi = mid; break; }
                    if (tot >= k) lo = mid; else hi = mid;
                }
                float tv = __uint_as_float(hi);
                float s = 0.f; int ct = 0;
                for (int i = 0; i < 32; i++) {
                    float4 r = v4[i * 256 + tid];
                    if (r.x > tv) { s += r.x; ct++; }
                    if (r.y > tv) { s += r.y; ct++; }
                    if (r.z > tv) { s += r.z; ct++; }
                    if (r.w > tv) { s += r.w; ct++; }
                }
#pragma unroll
                for (int off = 32; off > 0; off >>= 1) {
                    s += __shfl_down(s, off, 64); ct += __shfl_down(ct, off, 64);
                }
                if (lane == 0) { fred[wv] = s; ired[wv] = ct; }
                __syncthreads();
                if (tid == 0) {
                    float st = fred[0] + fred[1] + fred[2] + fred[3];
                    int ctt = ired[0] + ired[1] + ired[2] + ired[3];
                    atomicAdd(ce_t, st + (float)(k - ctt) * tv);
                }
            }
        }

        // ---------- finalize: 32nd finishing stage-3 block writes out ----------
        __syncthreads();
        if (tid == 0) {
            __threadfence();
            int old = __hip_atomic_fetch_add(done, 1, __ATOMIC_ACQ_REL, __HIP_MEMORY_SCOPE_AGENT);
            if (old == Bn - 1) {
                __threadfence();
                float N = (float)(*np_tot);
                out[0] = *loss_l_t / N;
                out[1] = *ce_t / N;
            }
        }
    }
}

extern "C" void kernel_launch(void* const* d_in, const int* in_sizes, int n_in,
                              void* d_out, int out_size, void* d_ws, size_t ws_size,
                              hipStream_t stream) {
    const float*  loc     = (const float*)d_in[0];   // (B,P,3)
    const float4* conf4   = (const float4*)d_in[1];  // (B,P,2)
    const float4* priors  = (const float4*)d_in[2];  // (P,4)
    const float*  targets = (const float*)d_in[3];   // (B,O,5)
    float* out = (float*)d_out;

    char* ws = (char*)d_ws;
    unsigned long long* bpm = (unsigned long long*)ws;
    int*   num_pos  = (int*)(ws + 8192);
    float* loss_l_t = (float*)(ws + 8320);
    float* ce_t     = (float*)(ws + 8324);
    int*   np_tot   = (int*)(ws + 8328);
    int*   done     = (int*)(ws + 8332);
    int*   barc     = (int*)(ws + 8448);
    int*   hist     = (int*)(ws + 16384);
    float* ce_mine  = (float*)(ws + 16384 + (size_t)Bn * NBINS * 4);

    // zero bpm/accumulators/counters/histogram (ws is poisoned 0xAA)
    hipMemsetAsync(ws, 0, 16384 + (size_t)Bn * NBINS * 4, stream);

    hipLaunchKernelGGL(fused, dim3(NBLK), dim3(256), 0, stream,
                       loc, conf4, priors, targets, bpm, num_pos,
                       loss_l_t, ce_t, np_tot, done, barc, hist, ce_mine, out);
}